// Round 10
// baseline (228.541 us; speedup 1.0000x reference)
//
#include <hip/hip_runtime.h>
#include <hip/hip_bf16.h>
#include <stdint.h>

typedef __bf16 bf16;
typedef bf16 bf16x8 __attribute__((ext_vector_type(8)));
typedef bf16 bf16x4 __attribute__((ext_vector_type(4)));
typedef float f32x4 __attribute__((ext_vector_type(4)));

#define MFMA16(a, b, c) __builtin_amdgcn_mfma_f32_16x16x32_bf16(a, b, c, 0, 0, 0)

static __device__ __forceinline__ bf16 f2b(float f) { return (bf16)f; }
static __device__ __forceinline__ float b2f(bf16 v) { return (float)v; }

// async global->LDS, 16B per lane. dst is wave-uniform base; HW adds lane*16.
static __device__ __forceinline__ void gload16(const void* src, void* dst) {
    __builtin_amdgcn_global_load_lds(
        (const __attribute__((address_space(1))) uint32_t*)src,
        (__attribute__((address_space(3))) uint32_t*)dst, 16, 0, 0);
}

// pack 2 f32 -> u32 of 2 bf16 (lo = src0, hi = src1); no builtin on gfx950
static __device__ __forceinline__ uint32_t cvtpk(float lo, float hi) {
    uint32_t r;
    asm volatile("v_cvt_pk_bf16_f32 %0, %1, %2" : "=v"(r) : "v"(lo), "v"(hi));
    return r;
}

// ---------------- fused fp32 -> bf16 conversion ----------------
__global__ void cvt_all(const float* __restrict__ x,  const float* __restrict__ wq,
                        const float* __restrict__ wk, const float* __restrict__ wv,
                        bf16* __restrict__ xb,  bf16* __restrict__ wqb,
                        bf16* __restrict__ wkb, bf16* __restrict__ wvb) {
    int i = blockIdx.x * blockDim.x + threadIdx.x;
    const float* src; bf16* dst; int off;
    if (i < 2097152)      { src = x;  dst = xb;  off = i; }
    else if (i < 3145728) { src = wq; dst = wqb; off = i - 2097152; }
    else if (i < 4194304) { src = wk; dst = wkb; off = i - 3145728; }
    else                  { src = wv; dst = wvb; off = i - 4194304; }
    float4 v = reinterpret_cast<const float4*>(src)[off];
    bf16x4 o;
    o[0] = f2b(v.x); o[1] = f2b(v.y); o[2] = f2b(v.z); o[3] = f2b(v.w);
    reinterpret_cast<bf16x4*>(dst)[off] = o;
}

// ---------------- RoPE cos/sin table ----------------
__global__ void rope_table(float2* __restrict__ tbl) {
    int t = blockIdx.x * blockDim.x + threadIdx.x;
    int i = t & 63;
    int s = t >> 6;
    float theta = expf(-9.210340371976184f * (float)(2 * i) * (1.0f / 128.0f));
    float freq = (float)s * theta;
    float sv, cv;
    sincosf(freq, &sv, &cv);
    tbl[t] = make_float2(cv, sv);
}

// ---------------- fused QKV GEMM: 256x256 tile (2x arithmetic intensity) ------------
// L2-BW analysis: 128^2 tile = 32KB DMA / 4.2 MFLOP per K-step -> L2-bound at
// ~95 GB/s/CU. 256^2 = 64KB / 16.8 MFLOP -> MFMA-bound. Round-6 flow: stage(t+1)
// before compute(t), one vmcnt(0)+barrier per K-step. 8 waves (2M x 4N), per-wave
// 128x64, acc[8][4]. LDS 128KB (1 blk/CU). Grid 384 = 16x8x3 (tail accepted).
// z=0: Q (+rope, exp2-scale); z=1: K (+rope); z=2: V transposed.
__global__ __launch_bounds__(512, 1) void gemm_qkv(const bf16* __restrict__ X,
                                                   const bf16* __restrict__ Wq,
                                                   const bf16* __restrict__ Wk,
                                                   const bf16* __restrict__ Wv,
                                                   bf16* __restrict__ Qm,
                                                   bf16* __restrict__ Km,
                                                   bf16* __restrict__ Vt,
                                                   const float2* __restrict__ tbl) {
    const int K = 2048;
    __shared__ bf16 As[2][256 * 64];   // 2 x 32KB
    __shared__ bf16 Bs[2][256 * 64];   // 2 x 32KB

    const int bid = blockIdx.x;
    const int wg  = (bid & 7) * 48 + (bid >> 3);   // XCD-contiguous, bijective (384%8==0)
    const int z   = wg >> 7;                       // 0..2
    const int t   = wg & 127;
    const int rbase = (t >> 3) * 256;              // 16 M-tiles
    const int cbase = (t & 7) * 256;               // 8 N-tiles

    const bf16* W = (z == 0) ? Wq : (z == 1) ? Wk : Wv;

    const int tid  = threadIdx.x;
    const int lane = tid & 63;
    const int w    = tid >> 6;      // 0..7
    const int wm   = w >> 2;        // 0..1 (M-half, 128 rows)
    const int wn   = w & 3;         // 0..3 (N quarter, 64 cols)
    const int l15  = lane & 15;
    const int l4   = lane >> 4;
    const int srow  = lane >> 3;
    const int sslot = lane & 7;

    auto stage = [&](int buf, int kt) {
#pragma unroll
        for (int i = 0; i < 4; ++i) {
            int c   = w * 4 + i;             // chunk 0..31 (8 rows x 1KB each)
            int row = c * 8 + srow;          // 0..255
            int gsl = sslot ^ (row & 7);
            gload16(&X[(size_t)(rbase + row) * K + kt + gsl * 8], (char*)As[buf] + c * 1024);
            gload16(&W[(size_t)(cbase + row) * K + kt + gsl * 8], (char*)Bs[buf] + c * 1024);
        }
    };
    auto rdA = [&](int buf, int mi, int ks) {
        int r    = wm * 128 + mi * 16 + l15;
        int phys = (ks * 4 + l4) ^ (r & 7);
        return *reinterpret_cast<const bf16x8*>((char*)As[buf] + r * 128 + phys * 16);
    };
    auto rdB = [&](int buf, int ni, int ks) {
        int r    = wn * 64 + ni * 16 + l15;
        int phys = (ks * 4 + l4) ^ (r & 7);
        return *reinterpret_cast<const bf16x8*>((char*)Bs[buf] + r * 128 + phys * 16);
    };

    f32x4 acc[8][4] = {};

    stage(0, 0);
    __syncthreads();
    int cur = 0;

    for (int kt = 0; kt < K; kt += 64) {
        if (kt + 64 < K) stage(cur ^ 1, kt + 64);

        bf16x8 bfr[4][2];
#pragma unroll
        for (int ni = 0; ni < 4; ++ni) {
            bfr[ni][0] = rdB(cur, ni, 0);
            bfr[ni][1] = rdB(cur, ni, 1);
        }
        // M-half 0: frags 0..3
        {
            bf16x8 af[4][2];
#pragma unroll
            for (int mi = 0; mi < 4; ++mi) {
                af[mi][0] = rdA(cur, mi, 0);
                af[mi][1] = rdA(cur, mi, 1);
            }
#pragma unroll
            for (int ks = 0; ks < 2; ++ks)
#pragma unroll
                for (int mi = 0; mi < 4; ++mi)
#pragma unroll
                    for (int ni = 0; ni < 4; ++ni)
                        acc[mi][ni] = MFMA16(af[mi][ks], bfr[ni][ks], acc[mi][ni]);
        }
        // M-half 1: frags 4..7
        {
            bf16x8 af[4][2];
#pragma unroll
            for (int mi = 0; mi < 4; ++mi) {
                af[mi][0] = rdA(cur, mi + 4, 0);
                af[mi][1] = rdA(cur, mi + 4, 1);
            }
#pragma unroll
            for (int ks = 0; ks < 2; ++ks)
#pragma unroll
                for (int mi = 0; mi < 4; ++mi)
#pragma unroll
                    for (int ni = 0; ni < 4; ++ni)
                        acc[mi + 4][ni] = MFMA16(af[mi][ks], bfr[ni][ks], acc[mi + 4][ni]);
        }

        __syncthreads();    // drains vmcnt: next tile staged; seals buffer reuse
        cur ^= 1;
    }

    if (z < 2) {
        bf16* Y = (z == 0) ? Qm : Km;
        const float scale = (z == 0) ? 0.1275174396094198f : 1.0f;  // log2e/sqrt(128) | 1
        const int odd = l15 & 1;
#pragma unroll
        for (int mi = 0; mi < 8; ++mi) {
            int r0 = rbase + wm * 128 + mi * 16 + l4 * 4;
#pragma unroll
            for (int i = 0; i < 4; ++i) {
                int r = r0 + i;
                int b = r >> 11, s = r & 2047;
#pragma unroll
                for (int ni = 0; ni < 4; ++ni) {
                    int n = cbase + wn * 64 + ni * 16 + l15;
                    int h = n >> 7, d = n & 127;
                    float v = acc[mi][ni][i];
                    float p = __shfl_xor(v, 1);
                    float2 cs = tbl[(s << 6) + (d >> 1)];
                    float res = v * cs.x + (odd ? p : -p) * cs.y;
                    Y[(((size_t)b * 16 + h) * 2048 + s) * 128 + d] = f2b(res * scale);
                }
            }
        }
    } else {
#pragma unroll
        for (int mi = 0; mi < 8; ++mi) {
            int r0 = rbase + wm * 128 + mi * 16 + l4 * 4;
            int b = r0 >> 11, s = r0 & 2047;
#pragma unroll
            for (int ni = 0; ni < 4; ++ni) {
                int n = cbase + wn * 64 + ni * 16 + l15;
                int h = n >> 7, d = n & 127;
                bf16x4 o;
#pragma unroll
                for (int i = 0; i < 4; ++i) o[i] = f2b(acc[mi][ni][i]);
                *reinterpret_cast<bf16x4*>(&Vt[(((size_t)b * 16 + h) * 128 + d) * 2048 + s]) = o;
            }
        }
    }
}

// ---------------- causal flash attention v5 (unchanged from round 9) -------------
__global__ __launch_bounds__(256, 4) void flash_attn(const bf16* __restrict__ Q,
                                                     const bf16* __restrict__ Km,
                                                     const bf16* __restrict__ Vt,
                                                     float* __restrict__ out) {
    __shared__ bf16 Ksh[64 * 128];    // 16KB, swizzled 16B slots
    __shared__ bf16 Vsh[128 * 64];    // 16KB, swizzled

    const int tid  = threadIdx.x;
    const int lane = tid & 63;
    const int w    = tid >> 6;
    const int l15  = lane & 15;
    const int l4   = lane >> 4;       // L (0..3)

    const int bx  = blockIdx.x;
    const int g   = (bx >> 5) & 7;
    const int seg = bx >> 8;
    const int qt  = (seg == 0) ? 31 - g : (seg == 1) ? g : (seg == 2) ? 23 - g : 8 + g;
    const int bh  = bx & 31;
    const int b   = bh >> 4, h = bh & 15;

    const bf16* Qb = Q  + (size_t)bh * 2048 * 128;
    const bf16* Kb = Km + (size_t)bh * 2048 * 128;
    const bf16* Vb = Vt + (size_t)bh * 128 * 2048;
    const int rw = qt * 64 + w * 16;

    auto stage = [&](int kvb) {
#pragma unroll
        for (int c4 = 0; c4 < 4; ++c4) {
            int c  = w * 4 + c4;
            int kr = c * 4 + (lane >> 4);
            int ks = (lane & 15) ^ (kr & 7);
            gload16((const char*)Kb + ((size_t)(kvb + kr) * 128 + ks * 8) * 2,
                    (char*)Ksh + c * 1024);
            int vr = c * 8 + (lane >> 3);
            int vs = (lane & 7) ^ (vr & 7);
            gload16((const char*)Vb + ((size_t)vr * 2048 + kvb + vs * 8) * 2,
                    (char*)Vsh + c * 1024);
        }
    };

    bf16x8 qf[4];
#pragma unroll
    for (int ks = 0; ks < 4; ++ks)
        qf[ks] = *reinterpret_cast<const bf16x8*>(
            &Qb[(size_t)(rw + l15) * 128 + ks * 32 + l4 * 8]);

    f32x4 o[8] = {};
    float mrow = -1e30f, lrow = 0.0f;     // state for q-row rw + l15

    const int xbase = l15 + ((lane >> 4) & 1) * 32;   // bpermute src base
    const bool hiL  = (lane >> 5) & 1;                // L>>1

    for (int t = 0; t <= qt; ++t) {
        const int kvb = t * 64;
        __syncthreads();
        stage(kvb);
        __syncthreads();

        const char* kb = (const char*)Ksh;
        f32x4 s4[4] = {};                 // s4[t4][i]: k = kvb + t4*16 + l4*4 + i
        __builtin_amdgcn_s_setprio(1);
#pragma unroll
        for (int t4 = 0; t4 < 4; ++t4) {
            int r = t4 * 16 + l15;
#pragma unroll
            for (int ks = 0; ks < 4; ++ks) {
                int phys = (ks * 4 + l4) ^ (r & 7);
                bf16x8 kf = *reinterpret_cast<const bf16x8*>(kb + r * 256 + phys * 16);
                s4[t4] = MFMA16(kf, qf[ks], s4[t4]);   // swapped: A=K, B=Q
            }
        }
        __builtin_amdgcn_s_setprio(0);

        if (t == qt) {   // causal mask: k > q
            int q = rw + l15;
#pragma unroll
            for (int t4 = 0; t4 < 4; ++t4)
#pragma unroll
                for (int i = 0; i < 4; ++i)
                    if (kvb + t4 * 16 + l4 * 4 + i > q) s4[t4][i] = -1e30f;
        }

        // in-lane softmax (exp2 domain; scores pre-scaled by log2e/sqrt(d))
        float sm = -1e30f;
#pragma unroll
        for (int t4 = 0; t4 < 4; ++t4)
#pragma unroll
            for (int i = 0; i < 4; ++i) sm = fmaxf(sm, s4[t4][i]);
        sm = fmaxf(sm, __shfl_xor(sm, 16));
        sm = fmaxf(sm, __shfl_xor(sm, 32));
        float nm    = fmaxf(mrow, sm);
        float alpha = __builtin_amdgcn_exp2f(mrow - nm);
        mrow = nm;
        float ps = 0.0f;
#pragma unroll
        for (int t4 = 0; t4 < 4; ++t4)
#pragma unroll
            for (int i = 0; i < 4; ++i) {
                float p = __builtin_amdgcn_exp2f(s4[t4][i] - nm);
                s4[t4][i] = p;
                ps += p;
            }
        ps += __shfl_xor(ps, 16);
        ps += __shfl_xor(ps, 32);
        lrow = lrow * alpha + ps;

        // rescale o: alpha of q' = l4*4+i lives in lane (lane&48)+(l4*4+i)
        float ai[4];
#pragma unroll
        for (int i = 0; i < 4; ++i)
            ai[i] = __shfl(alpha, (lane & 48) + l4 * 4 + i);
#pragma unroll
        for (int ds = 0; ds < 8; ++ds)
#pragma unroll
            for (int i = 0; i < 4; ++i) o[ds][i] *= ai[i];

        // pack P to bf16 pairs: own[t4*2+h] = {P[t4][2h] lo, P[t4][2h+1] hi}
        uint32_t own[8];
#pragma unroll
        for (int t4 = 0; t4 < 4; ++t4) {
            own[t4 * 2 + 0] = cvtpk(s4[t4][0], s4[t4][1]);
            own[t4 * 2 + 1] = cvtpk(s4[t4][2], s4[t4][3]);
        }
        // redistribute to PV A-frag: pa[ks2] = P[q=l15][k = ks2*32 + L*8 + j]
        bf16x8 pa[2];
#pragma unroll
        for (int ks2 = 0; ks2 < 2; ++ks2) {
            union { uint32_t u[4]; bf16x8 v; } pu;
#pragma unroll
            for (int s = 0; s < 4; ++s) {
                int srcl = xbase + 16 * (s >> 1);
                uint32_t ulo = (uint32_t)__shfl((int)own[ks2 * 4 + (s & 1)], srcl);
                uint32_t uhi = (uint32_t)__shfl((int)own[ks2 * 4 + 2 + (s & 1)], srcl);
                pu.u[s] = hiL ? uhi : ulo;
            }
            pa[ks2] = pu.v;
        }

        // PV: O += P @ V
        const char* vb = (const char*)Vsh;
        __builtin_amdgcn_s_setprio(1);
#pragma unroll
        for (int k2 = 0; k2 < 2; ++k2) {
#pragma unroll
            for (int ds = 0; ds < 8; ++ds) {
                int d     = ds * 16 + l15;
                int physv = (k2 * 4 + l4) ^ (d & 7);
                bf16x8 vf = *reinterpret_cast<const bf16x8*>(vb + d * 128 + physv * 16);
                o[ds] = MFMA16(pa[k2], vf, o[ds]);
            }
        }
        __builtin_amdgcn_s_setprio(0);
    }

    // epilogue: normalize + store fp32 (row q' = rw + l4*4 + i)
    float inv = 1.0f / lrow;
    float iv[4];
#pragma unroll
    for (int i = 0; i < 4; ++i)
        iv[i] = __shfl(inv, (lane & 48) + l4 * 4 + i);
#pragma unroll
    for (int i = 0; i < 4; ++i) {
        int row = rw + l4 * 4 + i;
#pragma unroll
        for (int ds = 0; ds < 8; ++ds)
            out[((size_t)b * 2048 + row) * 2048 + h * 128 + ds * 16 + l15] =
                o[ds][i] * iv[i];
    }
}

extern "C" void kernel_launch(void* const* d_in, const int* in_sizes, int n_in,
                              void* d_out, int out_size, void* d_ws, size_t ws_size,
                              hipStream_t stream) {
    const float* x  = (const float*)d_in[0];
    const float* Wq = (const float*)d_in[1];
    const float* Wk = (const float*)d_in[2];
    const float* Wv = (const float*)d_in[3];
    float* out = (float*)d_out;
    char* ws = (char*)d_ws;

    bf16* xb   = (bf16*)(ws + 0);
    bf16* wqb  = (bf16*)(ws + 16777216);
    bf16* wkb  = (bf16*)(ws + 25165824);
    bf16* wvb  = (bf16*)(ws + 33554432);
    bf16* Qm   = (bf16*)(ws + 41943040);
    bf16* Km   = (bf16*)(ws + 58720256);
    bf16* Vt   = (bf16*)(ws + 75497472);
    float2* tbl = (float2*)(ws + 92274688);

    cvt_all<<<20480, 256, 0, stream>>>(x, Wq, Wk, Wv, xb, wqb, wkb, wvb);
    rope_table<<<512, 256, 0, stream>>>(tbl);

    gemm_qkv<<<384, 512, 0, stream>>>(xb, wqb, wkb, wvb, Qm, Km, Vt, tbl);

    flash_attn<<<1024, 256, 0, stream>>>(Qm, Km, Vt, out);
}

// Round 11
// 218.952 us; speedup vs baseline: 1.0438x; 1.0438x over previous
//
#include <hip/hip_runtime.h>
#include <hip/hip_bf16.h>
#include <stdint.h>

typedef __bf16 bf16;
typedef bf16 bf16x8 __attribute__((ext_vector_type(8)));
typedef bf16 bf16x4 __attribute__((ext_vector_type(4)));
typedef float f32x4 __attribute__((ext_vector_type(4)));

#define MFMA16(a, b, c) __builtin_amdgcn_mfma_f32_16x16x32_bf16(a, b, c, 0, 0, 0)

static __device__ __forceinline__ bf16 f2b(float f) { return (bf16)f; }
static __device__ __forceinline__ float b2f(bf16 v) { return (float)v; }

// async global->LDS, 16B per lane. dst is wave-uniform base; HW adds lane*16.
static __device__ __forceinline__ void gload16(const void* src, void* dst) {
    __builtin_amdgcn_global_load_lds(
        (const __attribute__((address_space(1))) uint32_t*)src,
        (__attribute__((address_space(3))) uint32_t*)dst, 16, 0, 0);
}

// pack 2 f32 -> u32 of 2 bf16 (lo = src0, hi = src1); no builtin on gfx950
static __device__ __forceinline__ uint32_t cvtpk(float lo, float hi) {
    uint32_t r;
    asm volatile("v_cvt_pk_bf16_f32 %0, %1, %2" : "=v"(r) : "v"(lo), "v"(hi));
    return r;
}

// ---------------- fused fp32->bf16 conversion + RoPE table (one launch) ------------
__global__ void cvt_all(const float* __restrict__ x,  const float* __restrict__ wq,
                        const float* __restrict__ wk, const float* __restrict__ wv,
                        bf16* __restrict__ xb,  bf16* __restrict__ wqb,
                        bf16* __restrict__ wkb, bf16* __restrict__ wvb,
                        float2* __restrict__ tbl) {
    if (blockIdx.x >= 20480) {   // RoPE table: tbl[s][i] = {cos,sin}(s * theta_i)
        int t = (blockIdx.x - 20480) * blockDim.x + threadIdx.x;  // 0..131071
        int i = t & 63;
        int s = t >> 6;
        float theta = expf(-9.210340371976184f * (float)(2 * i) * (1.0f / 128.0f));
        float sv, cv;
        sincosf((float)s * theta, &sv, &cv);
        tbl[t] = make_float2(cv, sv);
        return;
    }
    int i = blockIdx.x * blockDim.x + threadIdx.x;
    const float* src; bf16* dst; int off;
    if (i < 2097152)      { src = x;  dst = xb;  off = i; }
    else if (i < 3145728) { src = wq; dst = wqb; off = i - 2097152; }
    else if (i < 4194304) { src = wk; dst = wkb; off = i - 3145728; }
    else                  { src = wv; dst = wvb; off = i - 4194304; }
    float4 v = reinterpret_cast<const float4*>(src)[off];
    bf16x4 o;
    o[0] = f2b(v.x); o[1] = f2b(v.y); o[2] = f2b(v.z); o[3] = f2b(v.w);
    reinterpret_cast<bf16x4*>(dst)[off] = o;
}

// ---------------- fused QKV GEMM: round-6 geometry + T4 counted vmcnt ------------
// 128x128 tile, BK=64, dbuf, 2 blocks/CU. Per K-step: stage(t+1) -> vmcnt(8)
// (waits ONLY tile t's loads; the 8 prefetch loads stay in flight across the
// barrier) -> raw s_barrier -> ds_read+MFMA -> raw s_barrier. This removes the
// __syncthreads vmcnt(0) drain of the prefetch (the m97 ~20% stall).
// z=0: Q (+rope, exp2 scale); z=1: K (+rope); z=2: V transposed.
__global__ __launch_bounds__(256) void gemm_qkv(const bf16* __restrict__ X,
                                                const bf16* __restrict__ Wq,
                                                const bf16* __restrict__ Wk,
                                                const bf16* __restrict__ Wv,
                                                bf16* __restrict__ Qm,
                                                bf16* __restrict__ Km,
                                                bf16* __restrict__ Vt,
                                                const float2* __restrict__ tbl) {
    const int K = 2048;
    __shared__ bf16 As[2][128 * 64];
    __shared__ bf16 Bs[2][128 * 64];

    const int z = blockIdx.z;
    const bf16* W = (z == 0) ? Wq : (z == 1) ? Wk : Wv;

    const int tid  = threadIdx.x;
    const int lane = tid & 63;
    const int w    = tid >> 6;
    const int wr   = (w >> 1) * 64;
    const int wc   = (w & 1) * 64;
    const int l15  = lane & 15;
    const int l4   = lane >> 4;
    const int rbase = blockIdx.x * 128;
    const int cbase = blockIdx.y * 128;

    const int srow  = lane >> 3;
    const int sslot = lane & 7;

    f32x4 acc[4][4] = {};

    auto stage = [&](int buf, int kt) {
#pragma unroll
        for (int i = 0; i < 4; ++i) {
            int c   = w * 4 + i;
            int row = c * 8 + srow;
            int gsl = sslot ^ (row & 7);
            gload16(&X[(size_t)(rbase + row) * K + kt + gsl * 8], (char*)As[buf] + c * 1024);
            gload16(&W[(size_t)(cbase + row) * K + kt + gsl * 8], (char*)Bs[buf] + c * 1024);
        }
    };

    auto compute = [&](int cur) {
        bf16x8 af[2][4], bfr[2][4];
#pragma unroll
        for (int ks = 0; ks < 2; ++ks) {
#pragma unroll
            for (int mi = 0; mi < 4; ++mi) {
                int r    = wr + mi * 16 + l15;
                int phys = (ks * 4 + l4) ^ (r & 7);
                af[ks][mi] = *reinterpret_cast<const bf16x8*>(
                    (char*)As[cur] + r * 128 + phys * 16);
            }
#pragma unroll
            for (int ni = 0; ni < 4; ++ni) {
                int r    = wc + ni * 16 + l15;
                int phys = (ks * 4 + l4) ^ (r & 7);
                bfr[ks][ni] = *reinterpret_cast<const bf16x8*>(
                    (char*)Bs[cur] + r * 128 + phys * 16);
            }
        }
#pragma unroll
        for (int ks = 0; ks < 2; ++ks)
#pragma unroll
            for (int mi = 0; mi < 4; ++mi)
#pragma unroll
                for (int ni = 0; ni < 4; ++ni)
                    acc[mi][ni] = MFMA16(af[ks][mi], bfr[ks][ni], acc[mi][ni]);
    };

    stage(0, 0);
    int cur = 0;

    for (int kt = 0; kt < K - 64; kt += 64) {
        stage(cur ^ 1, kt + 64);                       // 8 prefetch loads in flight
        asm volatile("s_waitcnt vmcnt(8)" ::: "memory"); // tile t's 8 oldest landed
        __builtin_amdgcn_s_barrier();                  // all waves: tile t ready
        asm volatile("" ::: "memory");
        compute(cur);
        asm volatile("" ::: "memory");
        __builtin_amdgcn_s_barrier();                  // all reads of cur done -> next
        cur ^= 1;                                      // iter may overwrite it
    }
    // epilogue: last tile, no prefetch
    asm volatile("s_waitcnt vmcnt(0)" ::: "memory");
    __builtin_amdgcn_s_barrier();
    asm volatile("" ::: "memory");
    compute(cur);

    if (z < 2) {
        bf16* Y = (z == 0) ? Qm : Km;
        const float scale = (z == 0) ? 0.1275174396094198f : 1.0f;  // log2e/sqrt(128) | 1
        const int odd = l15 & 1;
#pragma unroll
        for (int mi = 0; mi < 4; ++mi) {
            int r0 = rbase + wr + mi * 16 + l4 * 4;
#pragma unroll
            for (int i = 0; i < 4; ++i) {
                int r = r0 + i;
                int b = r >> 11, s = r & 2047;
#pragma unroll
                for (int ni = 0; ni < 4; ++ni) {
                    int n = cbase + wc + ni * 16 + l15;
                    int h = n >> 7, d = n & 127;
                    float v = acc[mi][ni][i];
                    float p = __shfl_xor(v, 1);
                    float2 cs = tbl[(s << 6) + (d >> 1)];
                    float res = v * cs.x + (odd ? p : -p) * cs.y;
                    Y[(((size_t)b * 16 + h) * 2048 + s) * 128 + d] = f2b(res * scale);
                }
            }
        }
    } else {
#pragma unroll
        for (int mi = 0; mi < 4; ++mi) {
            int r0 = rbase + wr + mi * 16 + l4 * 4;
            int b = r0 >> 11, s = r0 & 2047;
#pragma unroll
            for (int ni = 0; ni < 4; ++ni) {
                int n = cbase + wc + ni * 16 + l15;
                int h = n >> 7, d = n & 127;
                bf16x4 o;
#pragma unroll
                for (int i = 0; i < 4; ++i) o[i] = f2b(acc[mi][ni][i]);
                *reinterpret_cast<bf16x4*>(&Vt[(((size_t)b * 16 + h) * 128 + d) * 2048 + s]) = o;
            }
        }
    }
}

// ---------------- causal flash attention v5 (unchanged from round 9) -------------
__global__ __launch_bounds__(256, 4) void flash_attn(const bf16* __restrict__ Q,
                                                     const bf16* __restrict__ Km,
                                                     const bf16* __restrict__ Vt,
                                                     float* __restrict__ out) {
    __shared__ bf16 Ksh[64 * 128];    // 16KB, swizzled 16B slots
    __shared__ bf16 Vsh[128 * 64];    // 16KB, swizzled

    const int tid  = threadIdx.x;
    const int lane = tid & 63;
    const int w    = tid >> 6;
    const int l15  = lane & 15;
    const int l4   = lane >> 4;       // L (0..3)

    const int bx  = blockIdx.x;
    const int g   = (bx >> 5) & 7;
    const int seg = bx >> 8;
    const int qt  = (seg == 0) ? 31 - g : (seg == 1) ? g : (seg == 2) ? 23 - g : 8 + g;
    const int bh  = bx & 31;
    const int b   = bh >> 4, h = bh & 15;

    const bf16* Qb = Q  + (size_t)bh * 2048 * 128;
    const bf16* Kb = Km + (size_t)bh * 2048 * 128;
    const bf16* Vb = Vt + (size_t)bh * 128 * 2048;
    const int rw = qt * 64 + w * 16;

    auto stage = [&](int kvb) {
#pragma unroll
        for (int c4 = 0; c4 < 4; ++c4) {
            int c  = w * 4 + c4;
            int kr = c * 4 + (lane >> 4);
            int ks = (lane & 15) ^ (kr & 7);
            gload16((const char*)Kb + ((size_t)(kvb + kr) * 128 + ks * 8) * 2,
                    (char*)Ksh + c * 1024);
            int vr = c * 8 + (lane >> 3);
            int vs = (lane & 7) ^ (vr & 7);
            gload16((const char*)Vb + ((size_t)vr * 2048 + kvb + vs * 8) * 2,
                    (char*)Vsh + c * 1024);
        }
    };

    bf16x8 qf[4];
#pragma unroll
    for (int ks = 0; ks < 4; ++ks)
        qf[ks] = *reinterpret_cast<const bf16x8*>(
            &Qb[(size_t)(rw + l15) * 128 + ks * 32 + l4 * 8]);

    f32x4 o[8] = {};
    float mrow = -1e30f, lrow = 0.0f;     // state for q-row rw + l15

    const int xbase = l15 + ((lane >> 4) & 1) * 32;   // bpermute src base
    const bool hiL  = (lane >> 5) & 1;                // L>>1

    for (int t = 0; t <= qt; ++t) {
        const int kvb = t * 64;
        __syncthreads();
        stage(kvb);
        __syncthreads();

        const char* kb = (const char*)Ksh;
        f32x4 s4[4] = {};                 // s4[t4][i]: k = kvb + t4*16 + l4*4 + i
        __builtin_amdgcn_s_setprio(1);
#pragma unroll
        for (int t4 = 0; t4 < 4; ++t4) {
            int r = t4 * 16 + l15;
#pragma unroll
            for (int ks = 0; ks < 4; ++ks) {
                int phys = (ks * 4 + l4) ^ (r & 7);
                bf16x8 kf = *reinterpret_cast<const bf16x8*>(kb + r * 256 + phys * 16);
                s4[t4] = MFMA16(kf, qf[ks], s4[t4]);   // swapped: A=K, B=Q
            }
        }
        __builtin_amdgcn_s_setprio(0);

        if (t == qt) {   // causal mask: k > q
            int q = rw + l15;
#pragma unroll
            for (int t4 = 0; t4 < 4; ++t4)
#pragma unroll
                for (int i = 0; i < 4; ++i)
                    if (kvb + t4 * 16 + l4 * 4 + i > q) s4[t4][i] = -1e30f;
        }

        // in-lane softmax (exp2 domain; scores pre-scaled by log2e/sqrt(d))
        float sm = -1e30f;
#pragma unroll
        for (int t4 = 0; t4 < 4; ++t4)
#pragma unroll
            for (int i = 0; i < 4; ++i) sm = fmaxf(sm, s4[t4][i]);
        sm = fmaxf(sm, __shfl_xor(sm, 16));
        sm = fmaxf(sm, __shfl_xor(sm, 32));
        float nm    = fmaxf(mrow, sm);
        float alpha = __builtin_amdgcn_exp2f(mrow - nm);
        mrow = nm;
        float ps = 0.0f;
#pragma unroll
        for (int t4 = 0; t4 < 4; ++t4)
#pragma unroll
            for (int i = 0; i < 4; ++i) {
                float p = __builtin_amdgcn_exp2f(s4[t4][i] - nm);
                s4[t4][i] = p;
                ps += p;
            }
        ps += __shfl_xor(ps, 16);
        ps += __shfl_xor(ps, 32);
        lrow = lrow * alpha + ps;

        // rescale o: alpha of q' = l4*4+i lives in lane (lane&48)+(l4*4+i)
        float ai[4];
#pragma unroll
        for (int i = 0; i < 4; ++i)
            ai[i] = __shfl(alpha, (lane & 48) + l4 * 4 + i);
#pragma unroll
        for (int ds = 0; ds < 8; ++ds)
#pragma unroll
            for (int i = 0; i < 4; ++i) o[ds][i] *= ai[i];

        // pack P to bf16 pairs: own[t4*2+h] = {P[t4][2h] lo, P[t4][2h+1] hi}
        uint32_t own[8];
#pragma unroll
        for (int t4 = 0; t4 < 4; ++t4) {
            own[t4 * 2 + 0] = cvtpk(s4[t4][0], s4[t4][1]);
            own[t4 * 2 + 1] = cvtpk(s4[t4][2], s4[t4][3]);
        }
        // redistribute to PV A-frag: pa[ks2] = P[q=l15][k = ks2*32 + L*8 + j]
        bf16x8 pa[2];
#pragma unroll
        for (int ks2 = 0; ks2 < 2; ++ks2) {
            union { uint32_t u[4]; bf16x8 v; } pu;
#pragma unroll
            for (int s = 0; s < 4; ++s) {
                int srcl = xbase + 16 * (s >> 1);
                uint32_t ulo = (uint32_t)__shfl((int)own[ks2 * 4 + (s & 1)], srcl);
                uint32_t uhi = (uint32_t)__shfl((int)own[ks2 * 4 + 2 + (s & 1)], srcl);
                pu.u[s] = hiL ? uhi : ulo;
            }
            pa[ks2] = pu.v;
        }

        // PV: O += P @ V
        const char* vb = (const char*)Vsh;
        __builtin_amdgcn_s_setprio(1);
#pragma unroll
        for (int k2 = 0; k2 < 2; ++k2) {
#pragma unroll
            for (int ds = 0; ds < 8; ++ds) {
                int d     = ds * 16 + l15;
                int physv = (k2 * 4 + l4) ^ (d & 7);
                bf16x8 vf = *reinterpret_cast<const bf16x8*>(vb + d * 128 + physv * 16);
                o[ds] = MFMA16(pa[k2], vf, o[ds]);
            }
        }
        __builtin_amdgcn_s_setprio(0);
    }

    // epilogue: normalize + store fp32 (row q' = rw + l4*4 + i)
    float inv = 1.0f / lrow;
    float iv[4];
#pragma unroll
    for (int i = 0; i < 4; ++i)
        iv[i] = __shfl(inv, (lane & 48) + l4 * 4 + i);
#pragma unroll
    for (int i = 0; i < 4; ++i) {
        int row = rw + l4 * 4 + i;
#pragma unroll
        for (int ds = 0; ds < 8; ++ds)
            out[((size_t)b * 2048 + row) * 2048 + h * 128 + ds * 16 + l15] =
                o[ds][i] * iv[i];
    }
}

extern "C" void kernel_launch(void* const* d_in, const int* in_sizes, int n_in,
                              void* d_out, int out_size, void* d_ws, size_t ws_size,
                              hipStream_t stream) {
    const float* x  = (const float*)d_in[0];
    const float* Wq = (const float*)d_in[1];
    const float* Wk = (const float*)d_in[2];
    const float* Wv = (const float*)d_in[3];
    float* out = (float*)d_out;
    char* ws = (char*)d_ws;

    bf16* xb   = (bf16*)(ws + 0);
    bf16* wqb  = (bf16*)(ws + 16777216);
    bf16* wkb  = (bf16*)(ws + 25165824);
    bf16* wvb  = (bf16*)(ws + 33554432);
    bf16* Qm   = (bf16*)(ws + 41943040);
    bf16* Km   = (bf16*)(ws + 58720256);
    bf16* Vt   = (bf16*)(ws + 75497472);
    float2* tbl = (float2*)(ws + 92274688);

    cvt_all<<<20992, 256, 0, stream>>>(x, Wq, Wk, Wv, xb, wqb, wkb, wvb, tbl);

    dim3 gg(32, 16, 3);
    gemm_qkv<<<gg, 256, 0, stream>>>(xb, wqb, wkb, wvb, Qm, Km, Vt, tbl);

    flash_attn<<<1024, 256, 0, stream>>>(Qm, Km, Vt, out);
}

// Round 12
// 218.041 us; speedup vs baseline: 1.0482x; 1.0042x over previous
//
#include <hip/hip_runtime.h>
#include <hip/hip_bf16.h>
#include <stdint.h>

typedef __bf16 bf16;
typedef bf16 bf16x8 __attribute__((ext_vector_type(8)));
typedef bf16 bf16x4 __attribute__((ext_vector_type(4)));
typedef float f32x4 __attribute__((ext_vector_type(4)));

#define MFMA16(a, b, c) __builtin_amdgcn_mfma_f32_16x16x32_bf16(a, b, c, 0, 0, 0)

static __device__ __forceinline__ bf16 f2b(float f) { return (bf16)f; }
static __device__ __forceinline__ float b2f(bf16 v) { return (float)v; }

// async global->LDS, 16B per lane. dst is wave-uniform base; HW adds lane*16.
static __device__ __forceinline__ void gload16(const void* src, void* dst) {
    __builtin_amdgcn_global_load_lds(
        (const __attribute__((address_space(1))) uint32_t*)src,
        (__attribute__((address_space(3))) uint32_t*)dst, 16, 0, 0);
}

// pack 2 f32 -> u32 of 2 bf16 (lo = src0, hi = src1); no builtin on gfx950
static __device__ __forceinline__ uint32_t cvtpk(float lo, float hi) {
    uint32_t r;
    asm volatile("v_cvt_pk_bf16_f32 %0, %1, %2" : "=v"(r) : "v"(lo), "v"(hi));
    return r;
}

// ---------------- fused fp32->bf16 conversion + RoPE table (one launch) ------------
__global__ void cvt_all(const float* __restrict__ x,  const float* __restrict__ wq,
                        const float* __restrict__ wk, const float* __restrict__ wv,
                        bf16* __restrict__ xb,  bf16* __restrict__ wqb,
                        bf16* __restrict__ wkb, bf16* __restrict__ wvb,
                        float2* __restrict__ tbl) {
    if (blockIdx.x >= 20480) {   // RoPE table: tbl[s][i] = {cos,sin}(s * theta_i)
        int t = (blockIdx.x - 20480) * blockDim.x + threadIdx.x;  // 0..131071
        int i = t & 63;
        int s = t >> 6;
        float theta = expf(-9.210340371976184f * (float)(2 * i) * (1.0f / 128.0f));
        float sv, cv;
        sincosf((float)s * theta, &sv, &cv);
        tbl[t] = make_float2(cv, sv);
        return;
    }
    int i = blockIdx.x * blockDim.x + threadIdx.x;
    const float* src; bf16* dst; int off;
    if (i < 2097152)      { src = x;  dst = xb;  off = i; }
    else if (i < 3145728) { src = wq; dst = wqb; off = i - 2097152; }
    else if (i < 4194304) { src = wk; dst = wkb; off = i - 3145728; }
    else                  { src = wv; dst = wvb; off = i - 4194304; }
    float4 v = reinterpret_cast<const float4*>(src)[off];
    bf16x4 o;
    o[0] = f2b(v.x); o[1] = f2b(v.y); o[2] = f2b(v.z); o[3] = f2b(v.w);
    reinterpret_cast<bf16x4*>(dst)[off] = o;
}

// ---------------- fused QKV GEMM (round-6 2-phase dbuf: best measured, 128.8us) -----
__global__ __launch_bounds__(256) void gemm_qkv(const bf16* __restrict__ X,
                                                const bf16* __restrict__ Wq,
                                                const bf16* __restrict__ Wk,
                                                const bf16* __restrict__ Wv,
                                                bf16* __restrict__ Qm,
                                                bf16* __restrict__ Km,
                                                bf16* __restrict__ Vt,
                                                const float2* __restrict__ tbl) {
    const int K = 2048;
    __shared__ bf16 As[2][128 * 64];
    __shared__ bf16 Bs[2][128 * 64];

    const int z = blockIdx.z;
    const bf16* W = (z == 0) ? Wq : (z == 1) ? Wk : Wv;

    const int tid  = threadIdx.x;
    const int lane = tid & 63;
    const int w    = tid >> 6;
    const int wr   = (w >> 1) * 64;
    const int wc   = (w & 1) * 64;
    const int l15  = lane & 15;
    const int l4   = lane >> 4;
    const int rbase = blockIdx.x * 128;
    const int cbase = blockIdx.y * 128;

    const int srow  = lane >> 3;
    const int sslot = lane & 7;

    f32x4 acc[4][4] = {};

    auto stage = [&](int buf, int kt) {
#pragma unroll
        for (int i = 0; i < 4; ++i) {
            int c   = w * 4 + i;
            int row = c * 8 + srow;
            int gsl = sslot ^ (row & 7);
            gload16(&X[(size_t)(rbase + row) * K + kt + gsl * 8], (char*)As[buf] + c * 1024);
            gload16(&W[(size_t)(cbase + row) * K + kt + gsl * 8], (char*)Bs[buf] + c * 1024);
        }
    };

    stage(0, 0);
    __syncthreads();
    int cur = 0;

    for (int kt = 0; kt < K; kt += 64) {
        if (kt + 64 < K) stage(cur ^ 1, kt + 64);

        bf16x8 af[2][4], bfr[2][4];
#pragma unroll
        for (int ks = 0; ks < 2; ++ks) {
#pragma unroll
            for (int mi = 0; mi < 4; ++mi) {
                int r    = wr + mi * 16 + l15;
                int phys = (ks * 4 + l4) ^ (r & 7);
                af[ks][mi] = *reinterpret_cast<const bf16x8*>(
                    (char*)As[cur] + r * 128 + phys * 16);
            }
#pragma unroll
            for (int ni = 0; ni < 4; ++ni) {
                int r    = wc + ni * 16 + l15;
                int phys = (ks * 4 + l4) ^ (r & 7);
                bfr[ks][ni] = *reinterpret_cast<const bf16x8*>(
                    (char*)Bs[cur] + r * 128 + phys * 16);
            }
        }
#pragma unroll
        for (int ks = 0; ks < 2; ++ks)
#pragma unroll
            for (int mi = 0; mi < 4; ++mi)
#pragma unroll
                for (int ni = 0; ni < 4; ++ni)
                    acc[mi][ni] = MFMA16(af[ks][mi], bfr[ks][ni], acc[mi][ni]);

        __syncthreads();
        cur ^= 1;
    }

    if (z < 2) {
        bf16* Y = (z == 0) ? Qm : Km;
        const float scale = (z == 0) ? 0.1275174396094198f : 1.0f;  // log2e/sqrt(128) | 1
        const int odd = l15 & 1;
#pragma unroll
        for (int mi = 0; mi < 4; ++mi) {
            int r0 = rbase + wr + mi * 16 + l4 * 4;
#pragma unroll
            for (int i = 0; i < 4; ++i) {
                int r = r0 + i;
                int b = r >> 11, s = r & 2047;
#pragma unroll
                for (int ni = 0; ni < 4; ++ni) {
                    int n = cbase + wc + ni * 16 + l15;
                    int h = n >> 7, d = n & 127;
                    float v = acc[mi][ni][i];
                    float p = __shfl_xor(v, 1);
                    float2 cs = tbl[(s << 6) + (d >> 1)];
                    float res = v * cs.x + (odd ? p : -p) * cs.y;
                    Y[(((size_t)b * 16 + h) * 2048 + s) * 128 + d] = f2b(res * scale);
                }
            }
        }
    } else {
#pragma unroll
        for (int mi = 0; mi < 4; ++mi) {
            int r0 = rbase + wr + mi * 16 + l4 * 4;
            int b = r0 >> 11, s = r0 & 2047;
#pragma unroll
            for (int ni = 0; ni < 4; ++ni) {
                int n = cbase + wc + ni * 16 + l15;
                int h = n >> 7, d = n & 127;
                bf16x4 o;
#pragma unroll
                for (int i = 0; i < 4; ++i) o[i] = f2b(acc[mi][ni][i]);
                *reinterpret_cast<bf16x4*>(&Vt[(((size_t)b * 16 + h) * 128 + d) * 2048 + s]) = o;
            }
        }
    }
}

// ---------------- causal flash attention v6: 32 q-rows/wave ----------------
// Halves LDS-read bytes per MFMA vs v5: each K/V fragment read feeds 2 MFMAs
// (two 16-row q-sets per wave). QBLK=128, 4 waves x 32 rows, 512 blocks,
// 2 blocks/CU (VGPR-capped); blocks c and c+256 carry qt and 15-qt -> each
// CU's pair sums to uniform 34 kv-steps. In-register P per q-set (v5 scheme).
__global__ __launch_bounds__(256, 2) void flash_attn(const bf16* __restrict__ Q,
                                                     const bf16* __restrict__ Km,
                                                     const bf16* __restrict__ Vt,
                                                     float* __restrict__ out) {
    __shared__ bf16 Ksh[64 * 128];    // 16KB, swizzled 16B slots
    __shared__ bf16 Vsh[128 * 64];    // 16KB, swizzled

    const int tid  = threadIdx.x;
    const int lane = tid & 63;
    const int w    = tid >> 6;
    const int l15  = lane & 15;
    const int l4   = lane >> 4;       // L (0..3)

    const int bx = blockIdx.x;
    const int bh = bx & 31;
    const int qt = (bx < 256) ? (bx >> 5) : 23 - (bx >> 5);   // pair (c,c+256): qt,15-qt
    const int b  = bh >> 4, h = bh & 15;

    const bf16* Qb = Q  + (size_t)bh * 2048 * 128;
    const bf16* Kb = Km + (size_t)bh * 2048 * 128;
    const bf16* Vb = Vt + (size_t)bh * 128 * 2048;
    const int rw = qt * 128 + w * 32;     // wave's first q-row (owns 32 rows)

    auto stage = [&](int kvb) {
#pragma unroll
        for (int c4 = 0; c4 < 4; ++c4) {
            int c  = w * 4 + c4;
            int kr = c * 4 + (lane >> 4);
            int ks = (lane & 15) ^ (kr & 7);
            gload16((const char*)Kb + ((size_t)(kvb + kr) * 128 + ks * 8) * 2,
                    (char*)Ksh + c * 1024);
            int vr = c * 8 + (lane >> 3);
            int vs = (lane & 7) ^ (vr & 7);
            gload16((const char*)Vb + ((size_t)vr * 2048 + kvb + vs * 8) * 2,
                    (char*)Vsh + c * 1024);
        }
    };

    bf16x8 qf[2][4];
#pragma unroll
    for (int qi = 0; qi < 2; ++qi)
#pragma unroll
        for (int ks = 0; ks < 4; ++ks)
            qf[qi][ks] = *reinterpret_cast<const bf16x8*>(
                &Qb[(size_t)(rw + qi * 16 + l15) * 128 + ks * 32 + l4 * 8]);

    f32x4 o[2][8] = {};
    float mrow[2] = {-1e30f, -1e30f}, lrow[2] = {0.0f, 0.0f};

    const int xbase = l15 + (l4 & 1) * 32;   // bpermute src base
    const bool hiL  = (l4 >> 1) & 1;

    const int n = 2 * qt + 2;
    for (int t = 0; t < n; ++t) {
        const int kvb = t * 64;
        __syncthreads();              // prev compute done -> safe to overwrite LDS
        stage(kvb);
        __syncthreads();              // compiler drains vmcnt -> tile ready

        if (kvb > rw + 31) continue;  // wave-uniform: inactive trailing step

        // QK: swapped mfma(K, Q); kf shared by both q-sets
        const char* kb = (const char*)Ksh;
        f32x4 s4[2][4] = {};
        __builtin_amdgcn_s_setprio(1);
#pragma unroll
        for (int t4 = 0; t4 < 4; ++t4) {
            int r = t4 * 16 + l15;
#pragma unroll
            for (int ks = 0; ks < 4; ++ks) {
                int phys = (ks * 4 + l4) ^ (r & 7);
                bf16x8 kf = *reinterpret_cast<const bf16x8*>(kb + r * 256 + phys * 16);
                s4[0][t4] = MFMA16(kf, qf[0][ks], s4[0][t4]);
                s4[1][t4] = MFMA16(kf, qf[1][ks], s4[1][t4]);
            }
        }
        __builtin_amdgcn_s_setprio(0);

        if (kvb + 63 > rw) {   // diagonal region: causal mask (exact per-element)
#pragma unroll
            for (int qi = 0; qi < 2; ++qi) {
                int q = rw + qi * 16 + l15;
#pragma unroll
                for (int t4 = 0; t4 < 4; ++t4)
#pragma unroll
                    for (int i = 0; i < 4; ++i)
                        if (kvb + t4 * 16 + l4 * 4 + i > q) s4[qi][t4][i] = -1e30f;
            }
        }

        // per q-set: in-lane softmax + pack + redistribute to PV A-frag
        bf16x8 pa[2][2];
#pragma unroll
        for (int qi = 0; qi < 2; ++qi) {
            float sm = -1e30f;
#pragma unroll
            for (int t4 = 0; t4 < 4; ++t4)
#pragma unroll
                for (int i = 0; i < 4; ++i) sm = fmaxf(sm, s4[qi][t4][i]);
            sm = fmaxf(sm, __shfl_xor(sm, 16));
            sm = fmaxf(sm, __shfl_xor(sm, 32));
            float nm    = fmaxf(mrow[qi], sm);
            float alpha = __builtin_amdgcn_exp2f(mrow[qi] - nm);
            mrow[qi] = nm;
            float ps = 0.0f;
#pragma unroll
            for (int t4 = 0; t4 < 4; ++t4)
#pragma unroll
                for (int i = 0; i < 4; ++i) {
                    float p = __builtin_amdgcn_exp2f(s4[qi][t4][i] - nm);
                    s4[qi][t4][i] = p;
                    ps += p;
                }
            ps += __shfl_xor(ps, 16);
            ps += __shfl_xor(ps, 32);
            lrow[qi] = lrow[qi] * alpha + ps;

            float ai[4];
#pragma unroll
            for (int i = 0; i < 4; ++i)
                ai[i] = __shfl(alpha, (lane & 48) + l4 * 4 + i);
#pragma unroll
            for (int ds = 0; ds < 8; ++ds)
#pragma unroll
                for (int i = 0; i < 4; ++i) o[qi][ds][i] *= ai[i];

            uint32_t own[8];
#pragma unroll
            for (int t4 = 0; t4 < 4; ++t4) {
                own[t4 * 2 + 0] = cvtpk(s4[qi][t4][0], s4[qi][t4][1]);
                own[t4 * 2 + 1] = cvtpk(s4[qi][t4][2], s4[qi][t4][3]);
            }
#pragma unroll
            for (int ks2 = 0; ks2 < 2; ++ks2) {
                union { uint32_t u[4]; bf16x8 v; } pu;
#pragma unroll
                for (int s = 0; s < 4; ++s) {
                    int srcl = xbase + 16 * (s >> 1);
                    uint32_t ulo = (uint32_t)__shfl((int)own[ks2 * 4 + (s & 1)], srcl);
                    uint32_t uhi = (uint32_t)__shfl((int)own[ks2 * 4 + 2 + (s & 1)], srcl);
                    pu.u[s] = hiL ? uhi : ulo;
                }
                pa[qi][ks2] = pu.v;
            }
        }

        // PV: vf shared by both q-sets
        const char* vb = (const char*)Vsh;
        __builtin_amdgcn_s_setprio(1);
#pragma unroll
        for (int k2 = 0; k2 < 2; ++k2) {
#pragma unroll
            for (int ds = 0; ds < 8; ++ds) {
                int d     = ds * 16 + l15;
                int physv = (k2 * 4 + l4) ^ (d & 7);
                bf16x8 vf = *reinterpret_cast<const bf16x8*>(vb + d * 128 + physv * 16);
                o[0][ds] = MFMA16(pa[0][k2], vf, o[0][ds]);
                o[1][ds] = MFMA16(pa[1][k2], vf, o[1][ds]);
            }
        }
        __builtin_amdgcn_s_setprio(0);
    }

    // epilogue: normalize + store fp32 (rows rw + qi*16 + l4*4 + i)
#pragma unroll
    for (int qi = 0; qi < 2; ++qi) {
        float inv = 1.0f / lrow[qi];
        float iv[4];
#pragma unroll
        for (int i = 0; i < 4; ++i)
            iv[i] = __shfl(inv, (lane & 48) + l4 * 4 + i);
#pragma unroll
        for (int i = 0; i < 4; ++i) {
            int row = rw + qi * 16 + l4 * 4 + i;
#pragma unroll
            for (int ds = 0; ds < 8; ++ds)
                out[((size_t)b * 2048 + row) * 2048 + h * 128 + ds * 16 + l15] =
                    o[qi][ds][i] * iv[i];
        }
    }
}

extern "C" void kernel_launch(void* const* d_in, const int* in_sizes, int n_in,
                              void* d_out, int out_size, void* d_ws, size_t ws_size,
                              hipStream_t stream) {
    const float* x  = (const float*)d_in[0];
    const float* Wq = (const float*)d_in[1];
    const float* Wk = (const float*)d_in[2];
    const float* Wv = (const float*)d_in[3];
    float* out = (float*)d_out;
    char* ws = (char*)d_ws;

    bf16* xb   = (bf16*)(ws + 0);
    bf16* wqb  = (bf16*)(ws + 16777216);
    bf16* wkb  = (bf16*)(ws + 25165824);
    bf16* wvb  = (bf16*)(ws + 33554432);
    bf16* Qm   = (bf16*)(ws + 41943040);
    bf16* Km   = (bf16*)(ws + 58720256);
    bf16* Vt   = (bf16*)(ws + 75497472);
    float2* tbl = (float2*)(ws + 92274688);

    cvt_all<<<20992, 256, 0, stream>>>(x, Wq, Wk, Wv, xb, wqb, wkb, wvb, tbl);

    dim3 gg(32, 16, 3);
    gemm_qkv<<<gg, 256, 0, stream>>>(xb, wqb, wkb, wvb, Qm, Km, Vt, tbl);

    flash_attn<<<512, 256, 0, stream>>>(Qm, Km, Vt, out);
}

// Round 15
// 216.170 us; speedup vs baseline: 1.0572x; 1.0087x over previous
//
#include <hip/hip_runtime.h>
#include <hip/hip_bf16.h>
#include <stdint.h>

typedef __bf16 bf16;
typedef bf16 bf16x8 __attribute__((ext_vector_type(8)));
typedef bf16 bf16x4 __attribute__((ext_vector_type(4)));
typedef float f32x4 __attribute__((ext_vector_type(4)));

#define MFMA16(a, b, c) __builtin_amdgcn_mfma_f32_16x16x32_bf16(a, b, c, 0, 0, 0)

static __device__ __forceinline__ bf16 f2b(float f) { return (bf16)f; }
static __device__ __forceinline__ float b2f(bf16 v) { return (float)v; }

// async global->LDS, 16B per lane. dst is wave-uniform base; HW adds lane*16.
static __device__ __forceinline__ void gload16(const void* src, void* dst) {
    __builtin_amdgcn_global_load_lds(
        (const __attribute__((address_space(1))) uint32_t*)src,
        (__attribute__((address_space(3))) uint32_t*)dst, 16, 0, 0);
}

// pack 2 f32 -> u32 of 2 bf16 (lo = src0, hi = src1); no builtin on gfx950
static __device__ __forceinline__ uint32_t cvtpk(float lo, float hi) {
    uint32_t r;
    asm volatile("v_cvt_pk_bf16_f32 %0, %1, %2" : "=v"(r) : "v"(lo), "v"(hi));
    return r;
}

// ---------------- fused fp32 -> bf16 conversion ----------------
__global__ void cvt_all(const float* __restrict__ x,  const float* __restrict__ wq,
                        const float* __restrict__ wk, const float* __restrict__ wv,
                        bf16* __restrict__ xb,  bf16* __restrict__ wqb,
                        bf16* __restrict__ wkb, bf16* __restrict__ wvb) {
    int i = blockIdx.x * blockDim.x + threadIdx.x;
    const float* src; bf16* dst; int off;
    if (i < 2097152)      { src = x;  dst = xb;  off = i; }
    else if (i < 3145728) { src = wq; dst = wqb; off = i - 2097152; }
    else if (i < 4194304) { src = wk; dst = wkb; off = i - 3145728; }
    else                  { src = wv; dst = wvb; off = i - 4194304; }
    float4 v = reinterpret_cast<const float4*>(src)[off];
    bf16x4 o;
    o[0] = f2b(v.x); o[1] = f2b(v.y); o[2] = f2b(v.z); o[3] = f2b(v.w);
    reinterpret_cast<bf16x4*>(dst)[off] = o;
}

// ---------------- RoPE cos/sin table ----------------
__global__ void rope_table(float2* __restrict__ tbl) {
    int t = blockIdx.x * blockDim.x + threadIdx.x;
    int i = t & 63;
    int s = t >> 6;
    float theta = expf(-9.210340371976184f * (float)(2 * i) * (1.0f / 128.0f));
    float freq = (float)s * theta;
    float sv, cv;
    sincosf(freq, &sv, &cv);
    tbl[t] = make_float2(cv, sv);
}

// ---------------- fused QKV GEMM (round-6 2-phase dbuf: best measured) ------------
__global__ __launch_bounds__(256) void gemm_qkv(const bf16* __restrict__ X,
                                                const bf16* __restrict__ Wq,
                                                const bf16* __restrict__ Wk,
                                                const bf16* __restrict__ Wv,
                                                bf16* __restrict__ Qm,
                                                bf16* __restrict__ Km,
                                                bf16* __restrict__ Vt,
                                                const float2* __restrict__ tbl) {
    const int K = 2048;
    __shared__ bf16 As[2][128 * 64];
    __shared__ bf16 Bs[2][128 * 64];

    const int z = blockIdx.z;
    const bf16* W = (z == 0) ? Wq : (z == 1) ? Wk : Wv;

    const int tid  = threadIdx.x;
    const int lane = tid & 63;
    const int w    = tid >> 6;
    const int wr   = (w >> 1) * 64;
    const int wc   = (w & 1) * 64;
    const int l15  = lane & 15;
    const int l4   = lane >> 4;
    const int rbase = blockIdx.x * 128;
    const int cbase = blockIdx.y * 128;

    const int srow  = lane >> 3;
    const int sslot = lane & 7;

    f32x4 acc[4][4] = {};

    auto stage = [&](int buf, int kt) {
#pragma unroll
        for (int i = 0; i < 4; ++i) {
            int c   = w * 4 + i;
            int row = c * 8 + srow;
            int gsl = sslot ^ (row & 7);
            gload16(&X[(size_t)(rbase + row) * K + kt + gsl * 8], (char*)As[buf] + c * 1024);
            gload16(&W[(size_t)(cbase + row) * K + kt + gsl * 8], (char*)Bs[buf] + c * 1024);
        }
    };

    stage(0, 0);
    __syncthreads();
    int cur = 0;

    for (int kt = 0; kt < K; kt += 64) {
        if (kt + 64 < K) stage(cur ^ 1, kt + 64);

        bf16x8 af[2][4], bfr[2][4];
#pragma unroll
        for (int ks = 0; ks < 2; ++ks) {
#pragma unroll
            for (int mi = 0; mi < 4; ++mi) {
                int r    = wr + mi * 16 + l15;
                int phys = (ks * 4 + l4) ^ (r & 7);
                af[ks][mi] = *reinterpret_cast<const bf16x8*>(
                    (char*)As[cur] + r * 128 + phys * 16);
            }
#pragma unroll
            for (int ni = 0; ni < 4; ++ni) {
                int r    = wc + ni * 16 + l15;
                int phys = (ks * 4 + l4) ^ (r & 7);
                bfr[ks][ni] = *reinterpret_cast<const bf16x8*>(
                    (char*)Bs[cur] + r * 128 + phys * 16);
            }
        }
#pragma unroll
        for (int ks = 0; ks < 2; ++ks)
#pragma unroll
            for (int mi = 0; mi < 4; ++mi)
#pragma unroll
                for (int ni = 0; ni < 4; ++ni)
                    acc[mi][ni] = MFMA16(af[ks][mi], bfr[ks][ni], acc[mi][ni]);

        __syncthreads();
        cur ^= 1;
    }

    if (z < 2) {
        bf16* Y = (z == 0) ? Qm : Km;
        const float scale = (z == 0) ? 0.1275174396094198f : 1.0f;  // log2e/sqrt(128) | 1
        const int odd = l15 & 1;
#pragma unroll
        for (int mi = 0; mi < 4; ++mi) {
            int r0 = rbase + wr + mi * 16 + l4 * 4;
#pragma unroll
            for (int i = 0; i < 4; ++i) {
                int r = r0 + i;
                int b = r >> 11, s = r & 2047;
#pragma unroll
                for (int ni = 0; ni < 4; ++ni) {
                    int n = cbase + wc + ni * 16 + l15;
                    int h = n >> 7, d = n & 127;
                    float v = acc[mi][ni][i];
                    float p = __shfl_xor(v, 1);
                    float2 cs = tbl[(s << 6) + (d >> 1)];
                    float res = v * cs.x + (odd ? p : -p) * cs.y;
                    Y[(((size_t)b * 16 + h) * 2048 + s) * 128 + d] = f2b(res * scale);
                }
            }
        }
    } else {
#pragma unroll
        for (int mi = 0; mi < 4; ++mi) {
            int r0 = rbase + wr + mi * 16 + l4 * 4;
            int b = r0 >> 11, s = r0 & 2047;
#pragma unroll
            for (int ni = 0; ni < 4; ++ni) {
                int n = cbase + wc + ni * 16 + l15;
                int h = n >> 7, d = n & 127;
                bf16x4 o;
#pragma unroll
                for (int i = 0; i < 4; ++i) o[i] = f2b(acc[mi][ni][i]);
                *reinterpret_cast<bf16x4*>(&Vt[(((size_t)b * 16 + h) * 128 + d) * 2048 + s]) = o;
            }
        }
    }
}

// ---------------- causal flash attention v5: swapped QK^T + in-register P -------------
// S^T = mfma(A=K, B=Q): lane l15 owns q-row (rw+l15); its 16 scores live in
// s4[t4][i] with k = kvb + t4*16 + l4*4 + i. Softmax = in-lane trees + 2 shfl_xor.
// P packed via v_cvt_pk_bf16_f32, redistributed to PV A-fragment layout with
// shfl (no P LDS, no lgkmcnt drain). LDS 32KB -> 4+ blk/CU.
__global__ __launch_bounds__(256, 4) void flash_attn(const bf16* __restrict__ Q,
                                                     const bf16* __restrict__ Km,
                                                     const bf16* __restrict__ Vt,
                                                     float* __restrict__ out) {
    __shared__ bf16 Ksh[64 * 128];    // 16KB, swizzled 16B slots
    __shared__ bf16 Vsh[128 * 64];    // 16KB, swizzled

    const int tid  = threadIdx.x;
    const int lane = tid & 63;
    const int w    = tid >> 6;
    const int l15  = lane & 15;
    const int l4   = lane >> 4;       // L (0..3)

    const int bx  = blockIdx.x;
    const int g   = (bx >> 5) & 7;
    const int seg = bx >> 8;
    const int qt  = (seg == 0) ? 31 - g : (seg == 1) ? g : (seg == 2) ? 23 - g : 8 + g;
    const int bh  = bx & 31;
    const int b   = bh >> 4, h = bh & 15;

    const bf16* Qb = Q  + (size_t)bh * 2048 * 128;
    const bf16* Kb = Km + (size_t)bh * 2048 * 128;
    const bf16* Vb = Vt + (size_t)bh * 128 * 2048;
    const int rw = qt * 64 + w * 16;

    auto stage = [&](int kvb) {
#pragma unroll
        for (int c4 = 0; c4 < 4; ++c4) {
            int c  = w * 4 + c4;
            int kr = c * 4 + (lane >> 4);
            int ks = (lane & 15) ^ (kr & 7);
            gload16((const char*)Kb + ((size_t)(kvb + kr) * 128 + ks * 8) * 2,
                    (char*)Ksh + c * 1024);
            int vr = c * 8 + (lane >> 3);
            int vs = (lane & 7) ^ (vr & 7);
            gload16((const char*)Vb + ((size_t)vr * 2048 + kvb + vs * 8) * 2,
                    (char*)Vsh + c * 1024);
        }
    };

    bf16x8 qf[4];
#pragma unroll
    for (int ks = 0; ks < 4; ++ks)
        qf[ks] = *reinterpret_cast<const bf16x8*>(
            &Qb[(size_t)(rw + l15) * 128 + ks * 32 + l4 * 8]);

    f32x4 o[8] = {};
    float mrow = -1e30f, lrow = 0.0f;     // state for q-row rw + l15

    const int xbase = l15 + ((lane >> 4) & 1) * 32;   // bpermute src base
    const bool hiL  = (lane >> 5) & 1;                // L>>1

    for (int t = 0; t <= qt; ++t) {
        const int kvb = t * 64;
        __syncthreads();
        stage(kvb);
        __syncthreads();

        const char* kb = (const char*)Ksh;
        f32x4 s4[4] = {};                 // s4[t4][i]: k = kvb + t4*16 + l4*4 + i
        __builtin_amdgcn_s_setprio(1);
#pragma unroll
        for (int t4 = 0; t4 < 4; ++t4) {
            int r = t4 * 16 + l15;
#pragma unroll
            for (int ks = 0; ks < 4; ++ks) {
                int phys = (ks * 4 + l4) ^ (r & 7);
                bf16x8 kf = *reinterpret_cast<const bf16x8*>(kb + r * 256 + phys * 16);
                s4[t4] = MFMA16(kf, qf[ks], s4[t4]);   // swapped: A=K, B=Q
            }
        }
        __builtin_amdgcn_s_setprio(0);

        if (t == qt) {   // causal mask: k > q
            int q = rw + l15;
#pragma unroll
            for (int t4 = 0; t4 < 4; ++t4)
#pragma unroll
                for (int i = 0; i < 4; ++i)
                    if (kvb + t4 * 16 + l4 * 4 + i > q) s4[t4][i] = -1e30f;
        }

        // in-lane softmax (exp2 domain; scores pre-scaled by log2e/sqrt(d))
        float sm = -1e30f;
#pragma unroll
        for (int t4 = 0; t4 < 4; ++t4)
#pragma unroll
            for (int i = 0; i < 4; ++i) sm = fmaxf(sm, s4[t4][i]);
        sm = fmaxf(sm, __shfl_xor(sm, 16));
        sm = fmaxf(sm, __shfl_xor(sm, 32));
        float nm    = fmaxf(mrow, sm);
        float alpha = __builtin_amdgcn_exp2f(mrow - nm);
        mrow = nm;
        float ps = 0.0f;
#pragma unroll
        for (int t4 = 0; t4 < 4; ++t4)
#pragma unroll
            for (int i = 0; i < 4; ++i) {
                float p = __builtin_amdgcn_exp2f(s4[t4][i] - nm);
                s4[t4][i] = p;
                ps += p;
            }
        ps += __shfl_xor(ps, 16);
        ps += __shfl_xor(ps, 32);
        lrow = lrow * alpha + ps;

        // rescale o: alpha of q' = l4*4+i lives in lane (lane&48)+(l4*4+i)
        float ai[4];
#pragma unroll
        for (int i = 0; i < 4; ++i)
            ai[i] = __shfl(alpha, (lane & 48) + l4 * 4 + i);
#pragma unroll
        for (int ds = 0; ds < 8; ++ds)
#pragma unroll
            for (int i = 0; i < 4; ++i) o[ds][i] *= ai[i];

        // pack P to bf16 pairs: own[t4*2+h] = {P[t4][2h] lo, P[t4][2h+1] hi}
        uint32_t own[8];
#pragma unroll
        for (int t4 = 0; t4 < 4; ++t4) {
            own[t4 * 2 + 0] = cvtpk(s4[t4][0], s4[t4][1]);
            own[t4 * 2 + 1] = cvtpk(s4[t4][2], s4[t4][3]);
        }
        // redistribute to PV A-frag: pa[ks2] = P[q=l15][k = ks2*32 + L*8 + j]
        bf16x8 pa[2];
#pragma unroll
        for (int ks2 = 0; ks2 < 2; ++ks2) {
            union { uint32_t u[4]; bf16x8 v; } pu;
#pragma unroll
            for (int s = 0; s < 4; ++s) {
                int srcl = xbase + 16 * (s >> 1);
                uint32_t ulo = (uint32_t)__shfl((int)own[ks2 * 4 + (s & 1)], srcl);
                uint32_t uhi = (uint32_t)__shfl((int)own[ks2 * 4 + 2 + (s & 1)], srcl);
                pu.u[s] = hiL ? uhi : ulo;
            }
            pa[ks2] = pu.v;
        }

        // PV: O += P @ V
        const char* vb = (const char*)Vsh;
        __builtin_amdgcn_s_setprio(1);
#pragma unroll
        for (int k2 = 0; k2 < 2; ++k2) {
#pragma unroll
            for (int ds = 0; ds < 8; ++ds) {
                int d     = ds * 16 + l15;
                int physv = (k2 * 4 + l4) ^ (d & 7);
                bf16x8 vf = *reinterpret_cast<const bf16x8*>(vb + d * 128 + physv * 16);
                o[ds] = MFMA16(pa[k2], vf, o[ds]);
            }
        }
        __builtin_amdgcn_s_setprio(0);
    }

    // epilogue: normalize + store fp32 (row q' = rw + l4*4 + i)
    float inv = 1.0f / lrow;
    float iv[4];
#pragma unroll
    for (int i = 0; i < 4; ++i)
        iv[i] = __shfl(inv, (lane & 48) + l4 * 4 + i);
#pragma unroll
    for (int i = 0; i < 4; ++i) {
        int row = rw + l4 * 4 + i;
#pragma unroll
        for (int ds = 0; ds < 8; ++ds)
            out[((size_t)b * 2048 + row) * 2048 + h * 128 + ds * 16 + l15] =
                o[ds][i] * iv[i];
    }
}

extern "C" void kernel_launch(void* const* d_in, const int* in_sizes, int n_in,
                              void* d_out, int out_size, void* d_ws, size_t ws_size,
                              hipStream_t stream) {
    const float* x  = (const float*)d_in[0];
    const float* Wq = (const float*)d_in[1];
    const float* Wk = (const float*)d_in[2];
    const float* Wv = (const float*)d_in[3];
    float* out = (float*)d_out;
    char* ws = (char*)d_ws;

    bf16* xb   = (bf16*)(ws + 0);
    bf16* wqb  = (bf16*)(ws + 16777216);
    bf16* wkb  = (bf16*)(ws + 25165824);
    bf16* wvb  = (bf16*)(ws + 33554432);
    bf16* Qm   = (bf16*)(ws + 41943040);
    bf16* Km   = (bf16*)(ws + 58720256);
    bf16* Vt   = (bf16*)(ws + 75497472);
    float2* tbl = (float2*)(ws + 92274688);

    cvt_all<<<20480, 256, 0, stream>>>(x, Wq, Wk, Wv, xb, wqb, wkb, wvb);
    rope_table<<<512, 256, 0, stream>>>(tbl);

    dim3 gg(32, 16, 3);
    gemm_qkv<<<gg, 256, 0, stream>>>(xb, wqb, wkb, wvb, Qm, Km, Vt, tbl);

    flash_attn<<<1024, 256, 0, stream>>>(Qm, Km, Vt, out);
}

// Round 16
// 212.828 us; speedup vs baseline: 1.0738x; 1.0157x over previous
//
#include <hip/hip_runtime.h>
#include <hip/hip_bf16.h>
#include <stdint.h>

typedef __bf16 bf16;
typedef bf16 bf16x8 __attribute__((ext_vector_type(8)));
typedef bf16 bf16x4 __attribute__((ext_vector_type(4)));
typedef float f32x4 __attribute__((ext_vector_type(4)));

#define MFMA16(a, b, c) __builtin_amdgcn_mfma_f32_16x16x32_bf16(a, b, c, 0, 0, 0)

static __device__ __forceinline__ bf16 f2b(float f) { return (bf16)f; }
static __device__ __forceinline__ float b2f(bf16 v) { return (float)v; }

// async global->LDS, 16B per lane. dst is wave-uniform base; HW adds lane*16.
static __device__ __forceinline__ void gload16(const void* src, void* dst) {
    __builtin_amdgcn_global_load_lds(
        (const __attribute__((address_space(1))) uint32_t*)src,
        (__attribute__((address_space(3))) uint32_t*)dst, 16, 0, 0);
}

// pack 2 f32 -> u32 of 2 bf16 (lo = src0, hi = src1); no builtin on gfx950
static __device__ __forceinline__ uint32_t cvtpk(float lo, float hi) {
    uint32_t r;
    asm volatile("v_cvt_pk_bf16_f32 %0, %1, %2" : "=v"(r) : "v"(lo), "v"(hi));
    return r;
}

// ---------------- fused fp32->bf16 conversion + RoPE table (one launch) ------------
__global__ void cvt_all(const float* __restrict__ x,  const float* __restrict__ wq,
                        const float* __restrict__ wk, const float* __restrict__ wv,
                        bf16* __restrict__ xb,  bf16* __restrict__ wqb,
                        bf16* __restrict__ wkb, bf16* __restrict__ wvb,
                        float2* __restrict__ tbl) {
    if (blockIdx.x >= 20480) {   // RoPE table: tbl[s][i] = {cos,sin}(s * theta_i)
        int t = (blockIdx.x - 20480) * blockDim.x + threadIdx.x;  // 0..131071
        int i = t & 63;
        int s = t >> 6;
        float theta = expf(-9.210340371976184f * (float)(2 * i) * (1.0f / 128.0f));
        float sv, cv;
        sincosf((float)s * theta, &sv, &cv);
        tbl[t] = make_float2(cv, sv);
        return;
    }
    int i = blockIdx.x * blockDim.x + threadIdx.x;
    const float* src; bf16* dst; int off;
    if (i < 2097152)      { src = x;  dst = xb;  off = i; }
    else if (i < 3145728) { src = wq; dst = wqb; off = i - 2097152; }
    else if (i < 4194304) { src = wk; dst = wkb; off = i - 3145728; }
    else                  { src = wv; dst = wvb; off = i - 4194304; }
    float4 v = reinterpret_cast<const float4*>(src)[off];
    bf16x4 o;
    o[0] = f2b(v.x); o[1] = f2b(v.y); o[2] = f2b(v.z); o[3] = f2b(v.w);
    reinterpret_cast<bf16x4*>(dst)[off] = o;
}

// ---------------- fused QKV GEMM (round-6 2-phase dbuf: best measured) ------------
__global__ __launch_bounds__(256) void gemm_qkv(const bf16* __restrict__ X,
                                                const bf16* __restrict__ Wq,
                                                const bf16* __restrict__ Wk,
                                                const bf16* __restrict__ Wv,
                                                bf16* __restrict__ Qm,
                                                bf16* __restrict__ Km,
                                                bf16* __restrict__ Vt,
                                                const float2* __restrict__ tbl) {
    const int K = 2048;
    __shared__ bf16 As[2][128 * 64];
    __shared__ bf16 Bs[2][128 * 64];

    const int z = blockIdx.z;
    const bf16* W = (z == 0) ? Wq : (z == 1) ? Wk : Wv;

    const int tid  = threadIdx.x;
    const int lane = tid & 63;
    const int w    = tid >> 6;
    const int wr   = (w >> 1) * 64;
    const int wc   = (w & 1) * 64;
    const int l15  = lane & 15;
    const int l4   = lane >> 4;
    const int rbase = blockIdx.x * 128;
    const int cbase = blockIdx.y * 128;

    const int srow  = lane >> 3;
    const int sslot = lane & 7;

    f32x4 acc[4][4] = {};

    auto stage = [&](int buf, int kt) {
#pragma unroll
        for (int i = 0; i < 4; ++i) {
            int c   = w * 4 + i;
            int row = c * 8 + srow;
            int gsl = sslot ^ (row & 7);
            gload16(&X[(size_t)(rbase + row) * K + kt + gsl * 8], (char*)As[buf] + c * 1024);
            gload16(&W[(size_t)(cbase + row) * K + kt + gsl * 8], (char*)Bs[buf] + c * 1024);
        }
    };

    stage(0, 0);
    __syncthreads();
    int cur = 0;

    for (int kt = 0; kt < K; kt += 64) {
        if (kt + 64 < K) stage(cur ^ 1, kt + 64);

        bf16x8 af[2][4], bfr[2][4];
#pragma unroll
        for (int ks = 0; ks < 2; ++ks) {
#pragma unroll
            for (int mi = 0; mi < 4; ++mi) {
                int r    = wr + mi * 16 + l15;
                int phys = (ks * 4 + l4) ^ (r & 7);
                af[ks][mi] = *reinterpret_cast<const bf16x8*>(
                    (char*)As[cur] + r * 128 + phys * 16);
            }
#pragma unroll
            for (int ni = 0; ni < 4; ++ni) {
                int r    = wc + ni * 16 + l15;
                int phys = (ks * 4 + l4) ^ (r & 7);
                bfr[ks][ni] = *reinterpret_cast<const bf16x8*>(
                    (char*)Bs[cur] + r * 128 + phys * 16);
            }
        }
#pragma unroll
        for (int ks = 0; ks < 2; ++ks)
#pragma unroll
            for (int mi = 0; mi < 4; ++mi)
#pragma unroll
                for (int ni = 0; ni < 4; ++ni)
                    acc[mi][ni] = MFMA16(af[ks][mi], bfr[ks][ni], acc[mi][ni]);

        __syncthreads();
        cur ^= 1;
    }

    if (z < 2) {
        bf16* Y = (z == 0) ? Qm : Km;
        const float scale = (z == 0) ? 0.1275174396094198f : 1.0f;  // log2e/sqrt(128) | 1
        const int odd = l15 & 1;
#pragma unroll
        for (int mi = 0; mi < 4; ++mi) {
            int r0 = rbase + wr + mi * 16 + l4 * 4;
#pragma unroll
            for (int i = 0; i < 4; ++i) {
                int r = r0 + i;
                int b = r >> 11, s = r & 2047;
#pragma unroll
                for (int ni = 0; ni < 4; ++ni) {
                    int n = cbase + wc + ni * 16 + l15;
                    int h = n >> 7, d = n & 127;
                    float v = acc[mi][ni][i];
                    float p = __shfl_xor(v, 1);
                    float2 cs = tbl[(s << 6) + (d >> 1)];
                    float res = v * cs.x + (odd ? p : -p) * cs.y;
                    Y[(((size_t)b * 16 + h) * 2048 + s) * 128 + d] = f2b(res * scale);
                }
            }
        }
    } else {
#pragma unroll
        for (int mi = 0; mi < 4; ++mi) {
            int r0 = rbase + wr + mi * 16 + l4 * 4;
            int b = r0 >> 11, s = r0 & 2047;
#pragma unroll
            for (int ni = 0; ni < 4; ++ni) {
                int n = cbase + wc + ni * 16 + l15;
                int h = n >> 7, d = n & 127;
                bf16x4 o;
#pragma unroll
                for (int i = 0; i < 4; ++i) o[i] = f2b(acc[mi][ni][i]);
                *reinterpret_cast<bf16x4*>(&Vt[(((size_t)b * 16 + h) * 128 + d) * 2048 + s]) = o;
            }
        }
    }
}

// ---------------- causal flash attention v5: swapped QK^T + in-register P -------------
__global__ __launch_bounds__(256, 4) void flash_attn(const bf16* __restrict__ Q,
                                                     const bf16* __restrict__ Km,
                                                     const bf16* __restrict__ Vt,
                                                     float* __restrict__ out) {
    __shared__ bf16 Ksh[64 * 128];    // 16KB, swizzled 16B slots
    __shared__ bf16 Vsh[128 * 64];    // 16KB, swizzled

    const int tid  = threadIdx.x;
    const int lane = tid & 63;
    const int w    = tid >> 6;
    const int l15  = lane & 15;
    const int l4   = lane >> 4;       // L (0..3)

    const int bx  = blockIdx.x;
    const int g   = (bx >> 5) & 7;
    const int seg = bx >> 8;
    const int qt  = (seg == 0) ? 31 - g : (seg == 1) ? g : (seg == 2) ? 23 - g : 8 + g;
    const int bh  = bx & 31;
    const int b   = bh >> 4, h = bh & 15;

    const bf16* Qb = Q  + (size_t)bh * 2048 * 128;
    const bf16* Kb = Km + (size_t)bh * 2048 * 128;
    const bf16* Vb = Vt + (size_t)bh * 128 * 2048;
    const int rw = qt * 64 + w * 16;

    auto stage = [&](int kvb) {
#pragma unroll
        for (int c4 = 0; c4 < 4; ++c4) {
            int c  = w * 4 + c4;
            int kr = c * 4 + (lane >> 4);
            int ks = (lane & 15) ^ (kr & 7);
            gload16((const char*)Kb + ((size_t)(kvb + kr) * 128 + ks * 8) * 2,
                    (char*)Ksh + c * 1024);
            int vr = c * 8 + (lane >> 3);
            int vs = (lane & 7) ^ (vr & 7);
            gload16((const char*)Vb + ((size_t)vr * 2048 + kvb + vs * 8) * 2,
                    (char*)Vsh + c * 1024);
        }
    };

    bf16x8 qf[4];
#pragma unroll
    for (int ks = 0; ks < 4; ++ks)
        qf[ks] = *reinterpret_cast<const bf16x8*>(
            &Qb[(size_t)(rw + l15) * 128 + ks * 32 + l4 * 8]);

    f32x4 o[8] = {};
    float mrow = -1e30f, lrow = 0.0f;     // state for q-row rw + l15

    const int xbase = l15 + ((lane >> 4) & 1) * 32;   // bpermute src base
    const bool hiL  = (lane >> 5) & 1;                // L>>1

    for (int t = 0; t <= qt; ++t) {
        const int kvb = t * 64;
        __syncthreads();
        stage(kvb);
        __syncthreads();

        const char* kb = (const char*)Ksh;
        f32x4 s4[4] = {};                 // s4[t4][i]: k = kvb + t4*16 + l4*4 + i
        __builtin_amdgcn_s_setprio(1);
#pragma unroll
        for (int t4 = 0; t4 < 4; ++t4) {
            int r = t4 * 16 + l15;
#pragma unroll
            for (int ks = 0; ks < 4; ++ks) {
                int phys = (ks * 4 + l4) ^ (r & 7);
                bf16x8 kf = *reinterpret_cast<const bf16x8*>(kb + r * 256 + phys * 16);
                s4[t4] = MFMA16(kf, qf[ks], s4[t4]);   // swapped: A=K, B=Q
            }
        }
        __builtin_amdgcn_s_setprio(0);

        if (t == qt) {   // causal mask: k > q
            int q = rw + l15;
#pragma unroll
            for (int t4 = 0; t4 < 4; ++t4)
#pragma unroll
                for (int i = 0; i < 4; ++i)
                    if (kvb + t4 * 16 + l4 * 4 + i > q) s4[t4][i] = -1e30f;
        }

        // in-lane softmax (exp2 domain; scores pre-scaled by log2e/sqrt(d))
        float sm = -1e30f;
#pragma unroll
        for (int t4 = 0; t4 < 4; ++t4)
#pragma unroll
            for (int i = 0; i < 4; ++i) sm = fmaxf(sm, s4[t4][i]);
        sm = fmaxf(sm, __shfl_xor(sm, 16));
        sm = fmaxf(sm, __shfl_xor(sm, 32));
        float nm    = fmaxf(mrow, sm);
        float alpha = __builtin_amdgcn_exp2f(mrow - nm);
        mrow = nm;
        float ps = 0.0f;
#pragma unroll
        for (int t4 = 0; t4 < 4; ++t4)
#pragma unroll
            for (int i = 0; i < 4; ++i) {
                float p = __builtin_amdgcn_exp2f(s4[t4][i] - nm);
                s4[t4][i] = p;
                ps += p;
            }
        ps += __shfl_xor(ps, 16);
        ps += __shfl_xor(ps, 32);
        lrow = lrow * alpha + ps;

        // rescale o: alpha of q' = l4*4+i lives in lane (lane&48)+(l4*4+i)
        float ai[4];
#pragma unroll
        for (int i = 0; i < 4; ++i)
            ai[i] = __shfl(alpha, (lane & 48) + l4 * 4 + i);
#pragma unroll
        for (int ds = 0; ds < 8; ++ds)
#pragma unroll
            for (int i = 0; i < 4; ++i) o[ds][i] *= ai[i];

        // pack P to bf16 pairs: own[t4*2+h] = {P[t4][2h] lo, P[t4][2h+1] hi}
        uint32_t own[8];
#pragma unroll
        for (int t4 = 0; t4 < 4; ++t4) {
            own[t4 * 2 + 0] = cvtpk(s4[t4][0], s4[t4][1]);
            own[t4 * 2 + 1] = cvtpk(s4[t4][2], s4[t4][3]);
        }
        // redistribute to PV A-frag: pa[ks2] = P[q=l15][k = ks2*32 + L*8 + j]
        bf16x8 pa[2];
#pragma unroll
        for (int ks2 = 0; ks2 < 2; ++ks2) {
            union { uint32_t u[4]; bf16x8 v; } pu;
#pragma unroll
            for (int s = 0; s < 4; ++s) {
                int srcl = xbase + 16 * (s >> 1);
                uint32_t ulo = (uint32_t)__shfl((int)own[ks2 * 4 + (s & 1)], srcl);
                uint32_t uhi = (uint32_t)__shfl((int)own[ks2 * 4 + 2 + (s & 1)], srcl);
                pu.u[s] = hiL ? uhi : ulo;
            }
            pa[ks2] = pu.v;
        }

        // PV: O += P @ V
        const char* vb = (const char*)Vsh;
        __builtin_amdgcn_s_setprio(1);
#pragma unroll
        for (int k2 = 0; k2 < 2; ++k2) {
#pragma unroll
            for (int ds = 0; ds < 8; ++ds) {
                int d     = ds * 16 + l15;
                int physv = (k2 * 4 + l4) ^ (d & 7);
                bf16x8 vf = *reinterpret_cast<const bf16x8*>(vb + d * 128 + physv * 16);
                o[ds] = MFMA16(pa[k2], vf, o[ds]);
            }
        }
        __builtin_amdgcn_s_setprio(0);
    }

    // epilogue: normalize + store fp32 (row q' = rw + l4*4 + i)
    float inv = 1.0f / lrow;
    float iv[4];
#pragma unroll
    for (int i = 0; i < 4; ++i)
        iv[i] = __shfl(inv, (lane & 48) + l4 * 4 + i);
#pragma unroll
    for (int i = 0; i < 4; ++i) {
        int row = rw + l4 * 4 + i;
#pragma unroll
        for (int ds = 0; ds < 8; ++ds)
            out[((size_t)b * 2048 + row) * 2048 + h * 128 + ds * 16 + l15] =
                o[ds][i] * iv[i];
    }
}

extern "C" void kernel_launch(void* const* d_in, const int* in_sizes, int n_in,
                              void* d_out, int out_size, void* d_ws, size_t ws_size,
                              hipStream_t stream) {
    const float* x  = (const float*)d_in[0];
    const float* Wq = (const float*)d_in[1];
    const float* Wk = (const float*)d_in[2];
    const float* Wv = (const float*)d_in[3];
    float* out = (float*)d_out;
    char* ws = (char*)d_ws;

    bf16* xb   = (bf16*)(ws + 0);
    bf16* wqb  = (bf16*)(ws + 16777216);
    bf16* wkb  = (bf16*)(ws + 25165824);
    bf16* wvb  = (bf16*)(ws + 33554432);
    bf16* Qm   = (bf16*)(ws + 41943040);
    bf16* Km   = (bf16*)(ws + 58720256);
    bf16* Vt   = (bf16*)(ws + 75497472);
    float2* tbl = (float2*)(ws + 92274688);

    cvt_all<<<20992, 256, 0, stream>>>(x, Wq, Wk, Wv, xb, wqb, wkb, wvb, tbl);

    dim3 gg(32, 16, 3);
    gemm_qkv<<<gg, 256, 0, stream>>>(xb, wqb, wkb, wvb, Qm, Km, Vt, tbl);

    flash_attn<<<1024, 256, 0, stream>>>(Qm, Km, Vt, out);
}